// Round 1
// baseline (1064.794 us; speedup 1.0000x reference)
//
#include <hip/hip_runtime.h>

// BlockSparseLinear: out[M,N] = 2 * (x[M,K] @ (W .* mask)^T) + bias[N]
// M = 8*2048 = 16384, N = 4096, K = 4096, mask blocks 32x32 over (N/32, K/32).
// Strategy: normalize mask (format auto-detect) -> pre-convert masked W to bf16
// in d_ws -> bf16 MFMA GEMM (128x128 tile, BK=64, 4 waves, 16x16x32 frags),
// x converted fp32->bf16 during reg-staging. fp32 accumulate, epilogue 2*y+bias.

typedef short s16x8 __attribute__((ext_vector_type(8)));
typedef float f32x4 __attribute__((ext_vector_type(4)));
typedef unsigned short u16;

#define M_TOT 16384
#define N_TOT 4096
#define K_TOT 4096
#define MASK_DIM 128
#define LDS_STRIDE 72  // 64 bf16 payload + 8 pad -> 144B rows, breaks bank conflicts

__device__ __forceinline__ u16 f2bf(float f) {
  union { float f; unsigned u; } v; v.f = f;
  unsigned r = v.u + 0x7FFFu + ((v.u >> 16) & 1u);  // round-to-nearest-even
  return (u16)(r >> 16);
}

// ---------------------------------------------------------------------------
// Mask normalization. The harness may deliver the bool mask as 1-byte bools,
// int32, or float32. Detect by reading the first 256 words (1024 bytes, safe
// under every interpretation): int32/float 0/1 data makes every word 0, 1, or
// 0x3F800000; random 0/1 bytes make that all-256 coincidence ~8^-256.
// ---------------------------------------------------------------------------
__global__ void prep_mask_kernel(const unsigned char* __restrict__ m,
                                 unsigned char* __restrict__ outm) {
  __shared__ int s_ok[4];
  const int t = threadIdx.x;
  unsigned v = reinterpret_cast<const unsigned*>(m)[t];
  bool wordlike = (v <= 1u) || (v == 0x3F800000u);
  unsigned long long b = __ballot(wordlike);
  if ((t & 63) == 0) s_ok[t >> 6] = (b == ~0ull) ? 1 : 0;
  __syncthreads();
  const bool word_fmt = s_ok[0] && s_ok[1] && s_ok[2] && s_ok[3];
  for (int i = t; i < MASK_DIM * MASK_DIM; i += 256) {
    bool nz = word_fmt ? (reinterpret_cast<const unsigned*>(m)[i] != 0u)
                       : (m[i] != 0);
    outm[i] = nz ? 1 : 0;
  }
}

// ---------------------------------------------------------------------------
// W (fp32, [N][K]) -> masked bf16 [N][K] in workspace.
// ---------------------------------------------------------------------------
__global__ void prep_w_kernel(const float* __restrict__ w,
                              const unsigned char* __restrict__ mask8,
                              u16* __restrict__ wb) {
  const size_t e = ((size_t)blockIdx.x * blockDim.x + threadIdx.x) * 4;
  const int n = (int)(e >> 12);
  const int k = (int)(e & 4095);
  const float4 v = *reinterpret_cast<const float4*>(w + e);
  ushort4 bvec;
  if (mask8[(n >> 5) * MASK_DIM + (k >> 5)]) {
    bvec.x = f2bf(v.x); bvec.y = f2bf(v.y); bvec.z = f2bf(v.z); bvec.w = f2bf(v.w);
  } else {
    bvec.x = 0; bvec.y = 0; bvec.z = 0; bvec.w = 0;
  }
  *reinterpret_cast<ushort4*>(wb + e) = bvec;
}

// ---------------------------------------------------------------------------
// GEMM: C = 2 * A @ B^T + bias.  A = x (fp32->bf16 on the fly), B rows = W rows
// (K-major for both => both MFMA fragments are 8 contiguous K elems).
// Tile 128x128, BK=64, 256 threads = 4 waves in a 2x2 grid, each wave 64x64
// via acc[4][4] of 16x16x32 fragments.
// PREPPED: B from pre-converted bf16 ws. !PREPPED: B from raw fp32 W + mask.
// ---------------------------------------------------------------------------
template <bool PREPPED>
__global__ __launch_bounds__(256) void gemm_kernel(
    const float* __restrict__ x, const u16* __restrict__ wb,
    const float* __restrict__ wf, const unsigned char* __restrict__ mask8,
    const float* __restrict__ bias, float* __restrict__ out) {
  __shared__ __align__(16) u16 As[128 * LDS_STRIDE];
  __shared__ __align__(16) u16 Bs[128 * LDS_STRIDE];

  const int tid = threadIdx.x;
  const int lane = tid & 63;
  const int wave = tid >> 6;
  const int wr = wave >> 1;  // wave row (0..1), 64 C-rows each
  const int wc = wave & 1;   // wave col (0..1), 64 C-cols each

  // XCD-aware swizzle: gridDim.x = 4096, divisible by 8 -> bijective.
  int id = blockIdx.x;
  const int cpx = gridDim.x >> 3;
  id = (id & 7) * cpx + (id >> 3);
  const int bm = (id >> 5) << 7;  // 128 m-tiles
  const int bn = (id & 31) << 7;  // 32 n-tiles

  // fp32 staging geometry: 16 threads x 16B cover one 64-col row.
  const int arow = tid >> 4;         // 0..15
  const int acol = (tid & 15) << 2;  // 0..60 step 4
  // bf16 staging geometry: 8 threads x 16B (8 bf16) per row.
  const int brow = tid >> 3;         // 0..31
  const int bcol = (tid & 7) << 3;   // 0..56 step 8

  const int lrow = lane & 15;        // A-row / B-col within fragment
  const int lgo = (lane >> 4) << 3;  // k offset within 32-slice: 0,8,16,24

  f32x4 acc[4][4] = {};

  for (int k0 = 0; k0 < K_TOT; k0 += 64) {
    // ---- stage A (x): 128x64 fp32 -> bf16 LDS
#pragma unroll
    for (int r = 0; r < 8; ++r) {
      const int row = arow + r * 16;
      const float4 v = *reinterpret_cast<const float4*>(
          x + (size_t)(bm + row) * K_TOT + k0 + acol);
      ushort4 bvec;
      bvec.x = f2bf(v.x); bvec.y = f2bf(v.y); bvec.z = f2bf(v.z); bvec.w = f2bf(v.w);
      *reinterpret_cast<ushort4*>(&As[row * LDS_STRIDE + acol]) = bvec;
    }
    // ---- stage B (W rows bn..bn+128, cols k0..k0+64)
    if (PREPPED) {
#pragma unroll
      for (int r = 0; r < 4; ++r) {
        const int row = brow + r * 32;
        const s16x8 v = *reinterpret_cast<const s16x8*>(
            wb + (size_t)(bn + row) * K_TOT + k0 + bcol);
        *reinterpret_cast<s16x8*>(&Bs[row * LDS_STRIDE + bcol]) = v;
      }
    } else {
#pragma unroll
      for (int r = 0; r < 8; ++r) {
        const int row = arow + r * 16;
        const float4 v = *reinterpret_cast<const float4*>(
            wf + (size_t)(bn + row) * K_TOT + k0 + acol);
        ushort4 bvec;
        bvec.x = 0; bvec.y = 0; bvec.z = 0; bvec.w = 0;
        if (mask8[((bn + row) >> 5) * MASK_DIM + ((k0 + acol) >> 5)]) {
          bvec.x = f2bf(v.x); bvec.y = f2bf(v.y); bvec.z = f2bf(v.z); bvec.w = f2bf(v.w);
        }
        *reinterpret_cast<ushort4*>(&Bs[row * LDS_STRIDE + acol]) = bvec;
      }
    }
    __syncthreads();

#pragma unroll
    for (int ks = 0; ks < 2; ++ks) {
      s16x8 af[4], bfv[4];
#pragma unroll
      for (int m = 0; m < 4; ++m)
        af[m] = *reinterpret_cast<const s16x8*>(
            &As[(wr * 64 + m * 16 + lrow) * LDS_STRIDE + ks * 32 + lgo]);
#pragma unroll
      for (int n = 0; n < 4; ++n)
        bfv[n] = *reinterpret_cast<const s16x8*>(
            &Bs[(wc * 64 + n * 16 + lrow) * LDS_STRIDE + ks * 32 + lgo]);
#pragma unroll
      for (int m = 0; m < 4; ++m)
#pragma unroll
        for (int n = 0; n < 4; ++n)
          acc[m][n] = __builtin_amdgcn_mfma_f32_16x16x32_bf16(af[m], bfv[n],
                                                              acc[m][n], 0, 0, 0);
    }
    __syncthreads();
  }

  // ---- epilogue: out = 2*acc + bias. C/D frag: col = lane&15, row = (lane>>4)*4+j
#pragma unroll
  for (int n = 0; n < 4; ++n) {
    const int gcol = bn + wc * 64 + n * 16 + lrow;
    const float bv = bias[gcol];
#pragma unroll
    for (int m = 0; m < 4; ++m) {
      const int grow = bm + wr * 64 + m * 16 + ((lane >> 4) << 2);
#pragma unroll
      for (int j = 0; j < 4; ++j) {
        out[(size_t)(grow + j) * N_TOT + gcol] = 2.0f * acc[m][n][j] + bv;
      }
    }
  }
}

extern "C" void kernel_launch(void* const* d_in, const int* in_sizes, int n_in,
                              void* d_out, int out_size, void* d_ws, size_t ws_size,
                              hipStream_t stream) {
  const float* x = (const float*)d_in[0];
  const float* w = (const float*)d_in[1];
  const float* bias = (const float*)d_in[2];
  const unsigned char* mask_raw = (const unsigned char*)d_in[3];
  float* out = (float*)d_out;

  unsigned char* ws_mask = (unsigned char*)d_ws;               // 16 KiB
  u16* wb = (u16*)((char*)d_ws + 65536);                        // 32 MiB bf16 W
  const size_t need = 65536 + (size_t)N_TOT * K_TOT * sizeof(u16);

  prep_mask_kernel<<<1, 256, 0, stream>>>(mask_raw, ws_mask);

  if (ws_size >= need) {
    prep_w_kernel<<<(N_TOT * K_TOT) / (256 * 4), 256, 0, stream>>>(w, ws_mask, wb);
    gemm_kernel<true><<<(M_TOT / 128) * (N_TOT / 128), 256, 0, stream>>>(
        x, wb, nullptr, nullptr, bias, out);
  } else {
    gemm_kernel<false><<<(M_TOT / 128) * (N_TOT / 128), 256, 0, stream>>>(
        x, nullptr, w, ws_mask, bias, out);
  }
}